// Round 2
// baseline (1268.132 us; speedup 1.0000x reference)
//
#include <hip/hip_runtime.h>
#include <hip/hip_bf16.h>

// Problem constants (fixed by setup_inputs)
#define MDIM 8192    // B*S = 4*2048
#define KDIM 4096
#define NDIM 11008   // O
#define GDIM 32      // K/128 groups

// ---- 256x256x64 8-phase GEMM geometry (m201 template) ----
#define BM 256
#define BN 256
#define BK 64
#define NKT (KDIM / BK)      // 64 K-tiles
#define MT (MDIM / BM)       // 32
#define NT (NDIM / BN)       // 43
#define NWG (MT * NT)        // 1376 blocks (divisible by 8 -> XCD swizzle bijective)
#define CPX (NWG / 8)        // 172 blocks per XCD

typedef __attribute__((ext_vector_type(8))) short short8;
typedef __attribute__((ext_vector_type(16))) float f32x16;
typedef __attribute__((address_space(3))) unsigned char lds_u8;

__device__ __forceinline__ unsigned short f2bf(float f) {
    unsigned int u = __float_as_uint(f);
    u += 0x7FFFu + ((u >> 16) & 1u);   // round-to-nearest-even (inputs finite)
    return (unsigned short)(u >> 16);
}

__device__ __forceinline__ void async_ld16(const void* g, lds_u8* l) {
    __builtin_amdgcn_global_load_lds(
        (const __attribute__((address_space(1))) void*)g,
        (__attribute__((address_space(3))) void*)l, 16, 0, 0);
}

// stage one half-tile (128 rows x 64 cols bf16 = 16 KiB): 2 x global_load_lds / thread
__device__ __forceinline__ void stage_half(const unsigned short* src, lds_u8* dst) {
    async_ld16(src, dst);                             // rows  0..63  of the half
    async_ld16(src + (size_t)64 * KDIM, dst + 8192);  // rows 64..127
}

#define BAR()   __builtin_amdgcn_s_barrier()
#define FENCE() asm volatile("" ::: "memory")
#define LGKM0() asm volatile("s_waitcnt lgkmcnt(0)" ::: "memory")
#define LGKM4() asm volatile("s_waitcnt lgkmcnt(4)" ::: "memory")
#define LGKM8() asm volatile("s_waitcnt lgkmcnt(8)" ::: "memory")
#define VMW(n)  asm volatile("s_waitcnt vmcnt(" #n ")" ::: "memory")
#define SP1()   __builtin_amdgcn_s_setprio(1)
#define SP0()   __builtin_amdgcn_s_setprio(0)

// ---------------- Fused prepass: x fp32->bf16  AND  w int8*scale->bf16 ----------------
#define XBLOCKS ((MDIM * (size_t)KDIM) / 8 / 256)           // 16384
#define WBLOCKS ((NDIM * (size_t)KDIM) / 8 / 256)           // 22016
__global__ __launch_bounds__(256) void prep_kernel(const float* __restrict__ x,
                                                   const int* __restrict__ w,
                                                   const float* __restrict__ sc,
                                                   unsigned short* __restrict__ xb,
                                                   unsigned short* __restrict__ wb) {
    size_t b = blockIdx.x;
    if (b < XBLOCKS) {
        size_t i = (b * 256 + threadIdx.x) * 8;
        float4 f0 = *(const float4*)(x + i);
        float4 f1 = *(const float4*)(x + i + 4);
        union { unsigned short u[8]; uint4 v; } p;
        p.u[0] = f2bf(f0.x); p.u[1] = f2bf(f0.y); p.u[2] = f2bf(f0.z); p.u[3] = f2bf(f0.w);
        p.u[4] = f2bf(f1.x); p.u[5] = f2bf(f1.y); p.u[6] = f2bf(f1.z); p.u[7] = f2bf(f1.w);
        *(uint4*)(xb + i) = p.v;
    } else {
        size_t base = ((b - XBLOCKS) * 256 + threadIdx.x) * 8;  // 8 consecutive k, one group
        int o = (int)(base >> 12);             // /4096
        int k = (int)(base & 4095);
        float s = sc[o * GDIM + (k >> 7)];
        int4 w0 = *(const int4*)(w + base);
        int4 w1 = *(const int4*)(w + base + 4);
        union { unsigned short u[8]; uint4 v; } p;
        p.u[0] = f2bf((float)w0.x * s); p.u[1] = f2bf((float)w0.y * s);
        p.u[2] = f2bf((float)w0.z * s); p.u[3] = f2bf((float)w0.w * s);
        p.u[4] = f2bf((float)w1.x * s); p.u[5] = f2bf((float)w1.y * s);
        p.u[6] = f2bf((float)w1.z * s); p.u[7] = f2bf((float)w1.w * s);
        *(uint4*)(wb + base) = p.v;
    }
}

// ---------------- GEMM: C[M][N] = A[M][K] * B[N][K]^T, 256^2 8-phase, 32x32x16 MFMA ----
// 512 threads = 8 waves (2M x 4N); per-wave output 128x64 = 4 Mfrag x 2 Nfrag of 32x32.
// LDS 128 KiB: A[2 buf][16384e] at elem 0, B[2 buf][16384e] at elem 32768.
// 16B-chunk XOR swizzle (slot ^= row&7): pre-swizzled GLOBAL source (gload_lds dest
// linear, rule #21) + identical XOR on the ds_read side. 4 rows/slot at 32-row frags
// is an EVEN bank spread (8 accesses/bank = wave64 b128 structural minimum) -> no conflict.
// Per K-tile: 4 phases; counted vmcnt(4) once per tile (B half-tiles of kt+2 in flight).
__global__ __launch_bounds__(512, 2) void gemm256(const unsigned short* __restrict__ A,
                                                  const unsigned short* __restrict__ B,
                                                  float* __restrict__ C) {
    __shared__ unsigned short lds[65536];   // 128 KiB

    const int tid  = threadIdx.x;
    const int wave = tid >> 6;
    const int lane = tid & 63;
    const int wm = wave >> 2, wn = wave & 3;
    const int l31 = lane & 31;         // row (A) / col (B) within 32-frag
    const int hi  = lane >> 5;         // k-half within K=16 slice
    const int sw  = l31 & 7;           // read-side swizzle term (= row&7)

    // ---- block swizzle: XCD-contiguous chunks, M-fastest within XCD ----
    const int p    = blockIdx.x;
    const int tix  = (p & 7) * CPX + (p >> 3);
    const int bm   = tix & 31;
    const int bn   = tix >> 5;
    const int row0 = bm * BM, col0 = bn * BN;

    // ---- ds_read bases (ushort elements) ----
    int eoff[4];
#pragma unroll
    for (int ks = 0; ks < 4; ++ks) eoff[ks] = ((2 * ks + hi) ^ sw) * 8;
    const int rdA = wm * 8192 + l31 * 64;                 // within A buffer
    const int rdB = wn * 4096 + l31 * 64;                 // within B buffer

    // ---- staging mapping: thread t -> row t>>3, phys 16B-slot t&7 ----
    const int rA = tid >> 3;                        // 0..63
    const int cS = (tid & 7) ^ (rA & 7);            // logical slot held at phys slot
    const unsigned short* gA = A + (size_t)(row0 + rA) * KDIM + cS * 8;
    const unsigned short* gB = B + (size_t)(col0 + rA) * KDIM + cS * 8;
    lds_u8* L8A = (lds_u8*)lds + tid * 16;          // A region byte base + my chunk
    lds_u8* L8B = L8A + 65536;                      // B region

    // ---- prologue: tile0 (A,B -> buf0) + tile1 (B -> buf1) ----
    stage_half(gA,                      L8A);
    stage_half(gA + (size_t)128 * KDIM, L8A + 16384);
    stage_half(gB,                      L8B);
    stage_half(gB + (size_t)128 * KDIM, L8B + 16384);
    stage_half(gB + 64,                      L8B + 32768);
    stage_half(gB + (size_t)128 * KDIM + 64, L8B + 32768 + 16384);
    const unsigned short* pAg = gA + 64;     // A source for tile kt+1
    const unsigned short* pBg = gB + 128;    // B source for tile kt+2
    VMW(4);                                  // tile0 complete; tile1 B in flight
    BAR(); FENCE();

    short8 a[2][4], b[2][4];
    f32x16 acc[4][2];
#pragma unroll
    for (int mf = 0; mf < 4; ++mf)
#pragma unroll
        for (int nf = 0; nf < 2; ++nf)
#pragma unroll
            for (int r = 0; r < 16; ++r) acc[mf][nf][r] = 0.f;

    for (int kt = 0; kt < NKT; ++kt) {
        const int cur = kt & 1;
        const unsigned short* LcA = lds + cur * 16384 + rdA;
        const unsigned short* LcB = lds + 32768 + cur * 16384 + rdB;
        lds_u8* dA = L8A + (((kt + 1) & 1) << 15);   // A dest buffer (kt+1)
        lds_u8* dB = L8B + (cur << 15);              // B dest buffer (kt+2 == kt mod 2)
        const bool stA = (kt + 1 < NKT);
        const bool stB = (kt + 2 < NKT);

        // ---- phase 1: A frags 0-1 (8 rd) + B frags 0,1 (8 rd) | stage A-half0(kt+1) ----
#pragma unroll
        for (int m = 0; m < 2; ++m)
#pragma unroll
            for (int ks = 0; ks < 4; ++ks)
                a[m][ks] = *(const short8*)(LcA + m * 2048 + eoff[ks]);
#pragma unroll
        for (int ks = 0; ks < 4; ++ks) b[0][ks] = *(const short8*)(LcB + eoff[ks]);
#pragma unroll
        for (int ks = 0; ks < 4; ++ks) b[1][ks] = *(const short8*)(LcB + 2048 + eoff[ks]);
        if (stA) stage_half(pAg, dA);
        LGKM8();
        BAR();
        LGKM4();                 // a + b0 landed; b1's 4 reads drain under MFMA
        SP1();
#pragma unroll
        for (int ks = 0; ks < 4; ++ks)
#pragma unroll
            for (int m = 0; m < 2; ++m)
                acc[m][0] = __builtin_amdgcn_mfma_f32_32x32x16_bf16(
                    a[m][ks], b[0][ks], acc[m][0], 0, 0, 0);
        SP0();
        BAR(); FENCE();

        // ---- phase 2: no reads | stage A-half1(kt+1) ----
        if (stA) stage_half(pAg + (size_t)128 * KDIM, dA + 16384);
        BAR();
        LGKM0();                 // b1 guaranteed
        SP1();
#pragma unroll
        for (int ks = 0; ks < 4; ++ks)
#pragma unroll
            for (int m = 0; m < 2; ++m)
                acc[m][1] = __builtin_amdgcn_mfma_f32_32x32x16_bf16(
                    a[m][ks], b[1][ks], acc[m][1], 0, 0, 0);
        SP0();
        BAR(); FENCE();

        // ---- phase 3: A frags 2-3 (8 rd) | stage B-half0(kt+2) ----
#pragma unroll
        for (int m = 0; m < 2; ++m)
#pragma unroll
            for (int ks = 0; ks < 4; ++ks)
                a[m][ks] = *(const short8*)(LcA + (2 + m) * 2048 + eoff[ks]);
        if (stB) stage_half(pBg, dB);
        BAR();
        LGKM0();
        SP1();
#pragma unroll
        for (int ks = 0; ks < 4; ++ks)
#pragma unroll
            for (int m = 0; m < 2; ++m)
                acc[2 + m][0] = __builtin_amdgcn_mfma_f32_32x32x16_bf16(
                    a[m][ks], b[0][ks], acc[2 + m][0], 0, 0, 0);
        SP0();
        BAR(); FENCE();

        // ---- phase 4: no reads | stage B-half1(kt+2) | counted vmcnt gates tile kt+1 ----
        if (stB) stage_half(pBg + (size_t)128 * KDIM, dB + 16384);
        BAR();
        SP1();
#pragma unroll
        for (int ks = 0; ks < 4; ++ks)
#pragma unroll
            for (int m = 0; m < 2; ++m)
                acc[2 + m][1] = __builtin_amdgcn_mfma_f32_32x32x16_bf16(
                    a[m][ks], b[1][ks], acc[2 + m][1], 0, 0, 0);
        SP0();
        if (stB)      { VMW(4); }   // leave B halves of kt+2 (4 loads) in flight
        else if (stA) { VMW(0); }   // kt == NKT-2: drain (A of last tile)
        BAR(); FENCE();

        pAg += 64; pBg += 64;
    }

    // ---- epilogue: 32x32 C/D layout col=lane&31, row=(reg&3)+8*(reg>>2)+4*(lane>>5) ----
#pragma unroll
    for (int mf = 0; mf < 4; ++mf) {
        const int rb = row0 + wm * 128 + mf * 32 + 4 * hi;
#pragma unroll
        for (int nf = 0; nf < 2; ++nf) {
            const int c = col0 + wn * 64 + nf * 32 + l31;
            float* Cp = C + (size_t)rb * NDIM + c;
#pragma unroll
            for (int r = 0; r < 16; ++r) {
                const int dr = (r & 3) + 8 * (r >> 2);
                Cp[(size_t)dr * NDIM] = acc[mf][nf][r];
            }
        }
    }
}

// ---------------- Fallback (only if ws too small): naive fp32 ----------------
__global__ __launch_bounds__(256) void gemm_fallback(const float* __restrict__ X,
                                                     const int* __restrict__ W,
                                                     const float* __restrict__ S,
                                                     float* __restrict__ C) {
    int n = blockIdx.x * 256 + threadIdx.x;
    int m = blockIdx.y;
    if (n >= NDIM) return;
    const float* xr = X + (size_t)m * KDIM;
    const int*   wr = W + (size_t)n * KDIM;
    float acc = 0.f;
    for (int g = 0; g < GDIM; ++g) {
        float s = S[n * GDIM + g];
        float part = 0.f;
        for (int k = 0; k < 128; ++k)
            part += xr[g * 128 + k] * (float)wr[g * 128 + k];
        acc += part * s;
    }
    C[(size_t)m * NDIM + n] = acc;
}

extern "C" void kernel_launch(void* const* d_in, const int* in_sizes, int n_in,
                              void* d_out, int out_size, void* d_ws, size_t ws_size,
                              hipStream_t stream) {
    const float* x  = (const float*)d_in[0];
    const int*   w  = (const int*)d_in[1];
    const float* sc = (const float*)d_in[2];
    float* out = (float*)d_out;

    const size_t bytesA = (size_t)MDIM * KDIM * 2;   // 64 MiB bf16 x
    const size_t bytesB = (size_t)NDIM * KDIM * 2;   // 86 MiB bf16 dequant w

    if (ws_size >= bytesA + bytesB) {
        unsigned short* Abf = (unsigned short*)d_ws;
        unsigned short* Bbf = (unsigned short*)((char*)d_ws + bytesA);

        prep_kernel<<<(unsigned)(XBLOCKS + WBLOCKS), 256, 0, stream>>>(x, w, sc, Abf, Bbf);
        gemm256<<<NWG, 512, 0, stream>>>(Abf, Bbf, out);
    } else {
        dim3 grid((NDIM + 255) / 256, MDIM);
        gemm_fallback<<<grid, 256, 0, stream>>>(x, w, sc, out);
    }
}

// Round 3
// 1173.110 us; speedup vs baseline: 1.0810x; 1.0810x over previous
//
#include <hip/hip_runtime.h>
#include <hip/hip_bf16.h>

// Problem constants (fixed by setup_inputs)
#define MDIM 8192    // B*S = 4*2048
#define KDIM 4096
#define NDIM 11008   // O
#define GDIM 32      // K/128 groups

// ---- 256x256x64 8-phase GEMM geometry (m201 template) ----
#define BM 256
#define BN 256
#define BK 64
#define NKT (KDIM / BK)      // 64 K-tiles
#define MT (MDIM / BM)       // 32
#define NT (NDIM / BN)       // 43
#define NWG (MT * NT)        // 1376 blocks (divisible by 8 -> XCD swizzle bijective)
#define CPX (NWG / 8)        // 172 blocks per XCD

typedef __attribute__((ext_vector_type(8))) short short8;
typedef __attribute__((ext_vector_type(4))) float f32x4;
typedef __attribute__((address_space(3))) unsigned char lds_u8;

__device__ __forceinline__ unsigned short f2bf(float f) {
    unsigned int u = __float_as_uint(f);
    u += 0x7FFFu + ((u >> 16) & 1u);   // round-to-nearest-even (inputs finite)
    return (unsigned short)(u >> 16);
}

__device__ __forceinline__ void async_ld16(const void* g, lds_u8* l) {
    __builtin_amdgcn_global_load_lds(
        (const __attribute__((address_space(1))) void*)g,
        (__attribute__((address_space(3))) void*)l, 16, 0, 0);
}

// stage one half-tile (128 rows x 64 cols bf16 = 16 KiB): 2 x global_load_lds / thread
__device__ __forceinline__ void stage_half(const unsigned short* src, lds_u8* dst) {
    async_ld16(src, dst);                             // rows  0..63  of the half
    async_ld16(src + (size_t)64 * KDIM, dst + 8192);  // rows 64..127
}

#define BAR()   __builtin_amdgcn_s_barrier()
#define FENCE() asm volatile("" ::: "memory")
#define LGKM0() asm volatile("s_waitcnt lgkmcnt(0)" ::: "memory")
#define VMW(n)  asm volatile("s_waitcnt vmcnt(" #n ")" ::: "memory")
#define SP1()   __builtin_amdgcn_s_setprio(1)
#define SP0()   __builtin_amdgcn_s_setprio(0)

// load A fragments FB..FB+3 (both K=32 slices) from swizzled LDS
template<int FB>
__device__ __forceinline__ void ldA4(short8 (&a)[4][2],
                                     const unsigned short* p0,
                                     const unsigned short* p1) {
#pragma unroll
    for (int f = 0; f < 4; ++f) {
        a[f][0] = *(const short8*)(p0 + (FB + f) * 1024);
        a[f][1] = *(const short8*)(p1 + (FB + f) * 1024);
    }
}

// load B fragments NB..NB+1 (both K=32 slices)
template<int NB>
__device__ __forceinline__ void ldB2(short8 (&b)[4][2],
                                     const unsigned short* p0,
                                     const unsigned short* p1) {
#pragma unroll
    for (int n = 0; n < 2; ++n) {
        b[NB + n][0] = *(const short8*)(p0 + (NB + n) * 1024);
        b[NB + n][1] = *(const short8*)(p1 + (NB + n) * 1024);
    }
}

// one C-quadrant x K=64: 16 MFMA (ks outer -> consecutive MFMAs independent)
template<int FB, int NB>
__device__ __forceinline__ void mm16(f32x4 (&acc)[8][4],
                                     const short8 (&a)[4][2],
                                     const short8 (&b)[4][2]) {
#pragma unroll
    for (int ks = 0; ks < 2; ++ks)
#pragma unroll
        for (int f = 0; f < 4; ++f)
#pragma unroll
            for (int n = 0; n < 2; ++n)
                acc[FB + f][NB + n] = __builtin_amdgcn_mfma_f32_16x16x32_bf16(
                    a[f][ks], b[NB + n][ks], acc[FB + f][NB + n], 0, 0, 0);
}

// ---------------- Fused prepass: x fp32->bf16  AND  w int8*scale->bf16 ----------------
#define XBLOCKS ((MDIM * (size_t)KDIM) / 8 / 256)           // 16384
#define WBLOCKS ((NDIM * (size_t)KDIM) / 8 / 256)           // 22016
__global__ __launch_bounds__(256) void prep_kernel(const float* __restrict__ x,
                                                   const int* __restrict__ w,
                                                   const float* __restrict__ sc,
                                                   unsigned short* __restrict__ xb,
                                                   unsigned short* __restrict__ wb) {
    size_t b = blockIdx.x;
    if (b < XBLOCKS) {
        size_t i = (b * 256 + threadIdx.x) * 8;
        float4 f0 = *(const float4*)(x + i);
        float4 f1 = *(const float4*)(x + i + 4);
        union { unsigned short u[8]; uint4 v; } p;
        p.u[0] = f2bf(f0.x); p.u[1] = f2bf(f0.y); p.u[2] = f2bf(f0.z); p.u[3] = f2bf(f0.w);
        p.u[4] = f2bf(f1.x); p.u[5] = f2bf(f1.y); p.u[6] = f2bf(f1.z); p.u[7] = f2bf(f1.w);
        *(uint4*)(xb + i) = p.v;
    } else {
        size_t base = ((b - XBLOCKS) * 256 + threadIdx.x) * 8;  // 8 consecutive k, one group
        int o = (int)(base >> 12);             // /4096
        int k = (int)(base & 4095);
        float s = sc[o * GDIM + (k >> 7)];
        int4 w0 = *(const int4*)(w + base);
        int4 w1 = *(const int4*)(w + base + 4);
        union { unsigned short u[8]; uint4 v; } p;
        p.u[0] = f2bf((float)w0.x * s); p.u[1] = f2bf((float)w0.y * s);
        p.u[2] = f2bf((float)w0.z * s); p.u[3] = f2bf((float)w0.w * s);
        p.u[4] = f2bf((float)w1.x * s); p.u[5] = f2bf((float)w1.y * s);
        p.u[6] = f2bf((float)w1.z * s); p.u[7] = f2bf((float)w1.w * s);
        *(uint4*)(wb + base) = p.v;
    }
}

// ---------------- GEMM: C[M][N] = A[M][K] * B[N][K]^T, 256^2 8-phase ----------------
// 512 threads = 8 waves (2M x 4N); per-wave output 128x64 = acc[8][4] f32x4.
// LDS 128 KiB: A[2 buf][16384e] at elem 0, B[2 buf][16384e] at elem 32768.
// 16x16x32 MFMA + 3-bit 16B-chunk XOR swizzle: the measured-conflict-free combo (r1).
// Read batches evened to 8/4/8/4 per phase: next-tile b01 pre-read in ph4 after
// VMW(4)+BAR (publishes all waves' B(kt+1) stages) -> each batch hides under the
// previous MFMA cluster's queued pipe drain.
__global__ __launch_bounds__(512, 2) void gemm256(const unsigned short* __restrict__ A,
                                                  const unsigned short* __restrict__ B,
                                                  float* __restrict__ C) {
    __shared__ unsigned short lds[65536];   // 128 KiB

    const int tid  = threadIdx.x;
    const int wave = tid >> 6;
    const int lane = tid & 63;
    const int wm = wave >> 2, wn = wave & 3;
    const int q  = lane >> 4;          // k-quad within K=32 slice
    const int ml = lane & 15;          // m (A) / n (B) index within 16-tile
    const int s  = ml & 7;             // read-side swizzle term (= row&7)

    // ---- block swizzle: XCD-contiguous chunks, M-fastest within XCD ----
    const int p    = blockIdx.x;
    const int tix  = (p & 7) * CPX + (p >> 3);
    const int bm   = tix & 31;
    const int bn   = tix >> 5;
    const int row0 = bm * BM, col0 = bn * BN;

    // ---- ds_read bases (ushort elements) ----
    const int e0  = ((q    ) ^ s) * 8;             // ks=0 chunk, swizzled
    const int e1  = ((4 + q) ^ s) * 8;             // ks=1 chunk, swizzled
    const int rdA = wm * 8192 + ml * 64;
    const int rdB = 32768 + wn * 4096 + ml * 64;

    // ---- staging mapping: thread t -> row t>>3, phys 16B-slot t&7 ----
    const int rA = tid >> 3;                        // 0..63
    const int cS = (tid & 7) ^ (rA & 7);            // logical slot held at phys slot
    const unsigned short* gA = A + (size_t)(row0 + rA) * KDIM + cS * 8;
    const unsigned short* gB = B + (size_t)(col0 + rA) * KDIM + cS * 8;
    lds_u8* L8A = (lds_u8*)lds + tid * 16;          // A region byte base + my chunk
    lds_u8* L8B = L8A + 65536;                      // B region

    // ---- prologue: tile0 (A,B -> buf0) + tile1 (B -> buf1) ----
    stage_half(gA,                      L8A);
    stage_half(gA + (size_t)128 * KDIM, L8A + 16384);
    stage_half(gB,                      L8B);
    stage_half(gB + (size_t)128 * KDIM, L8B + 16384);
    stage_half(gB + 64,                      L8B + 32768);
    stage_half(gB + (size_t)128 * KDIM + 64, L8B + 32768 + 16384);
    const unsigned short* pAg = gA + 64;     // A source for tile kt+1
    const unsigned short* pBg = gB + 128;    // B source for tile kt+2
    VMW(4);                                  // tile0 complete; tile1 B in flight
    BAR(); FENCE();

    short8 a[4][2], b[4][2];
    f32x4 acc[8][4];
    const f32x4 z = {0.f, 0.f, 0.f, 0.f};
#pragma unroll
    for (int f = 0; f < 8; ++f)
#pragma unroll
        for (int n = 0; n < 4; ++n) acc[f][n] = z;

    // pre-read tile0's b01 (buf0)
    ldB2<0>(b, lds + rdB + e0, lds + rdB + e1);

    for (int kt = 0; kt < NKT; ++kt) {
        const int cur = kt & 1;
        const unsigned short* Lc  = lds + cur * 16384;
        const unsigned short* pA0 = Lc + rdA + e0;
        const unsigned short* pA1 = Lc + rdA + e1;
        const unsigned short* pB0 = Lc + rdB + e0;
        const unsigned short* pB1 = Lc + rdB + e1;
        const unsigned short* Ln  = lds + (cur ^ 1) * 16384;   // next tile's buffer
        const unsigned short* pB0n = Ln + rdB + e0;
        const unsigned short* pB1n = Ln + rdB + e1;
        lds_u8* dA = L8A + (((kt + 1) & 1) << 15);   // A dest buffer (kt+1)
        lds_u8* dB = L8B + ((cur) << 15);            // B dest buffer (kt+2 == kt mod 2)
        const bool stA = (kt + 1 < NKT);
        const bool stB = (kt + 2 < NKT);

        // ---- phase 1: ldA frags0-3 (8 rd; b01 already in regs) | stage A-half0(kt+1) ----
        ldA4<0>(a, pA0, pA1);
        if (stA) stage_half(pAg, dA);
        BAR();
        LGKM0();                  // a03 + (prologue/ph4) b01 drained
        SP1();
        mm16<0, 0>(acc, a, b);
        SP0();
        BAR(); FENCE();

        // ---- phase 2: ldB frags2-3 (4 rd) | stage A-half1(kt+1) ----
        ldB2<2>(b, pB0, pB1);
        if (stA) stage_half(pAg + (size_t)128 * KDIM, dA + 16384);
        BAR();
        LGKM0();                  // b23 drained (required before ph3's in-place B-stage)
        SP1();
        mm16<0, 2>(acc, a, b);
        SP0();
        BAR(); FENCE();

        // ---- phase 3: ldA frags4-7 (8 rd; overwrites a after C2 issue) | stage B-half0(kt+2) ----
        ldA4<4>(a, pA0, pA1);
        if (stB) stage_half(pBg, dB);
        BAR();
        LGKM0();
        SP1();
        mm16<4, 0>(acc, a, b);    // a47 x b01 (b01 still live)
        SP0();
        BAR(); FENCE();

        // ---- phase 4: stage B-half1(kt+2); VMW publishes tile kt+1; pre-read b01(kt+1) ----
        if (stB) stage_half(pBg + (size_t)128 * KDIM, dB + 16384);
        if (stB)      { VMW(4); }   // drains B(kt+1)+A(kt+1); B(kt+2) 4 loads in flight
        else if (stA) { VMW(0); }   // kt == NKT-2: drain (A of last tile)
        BAR(); FENCE();             // all waves' kt+1 stages now visible
        if (stA) ldB2<0>(b, pB0n, pB1n);   // 4 rd: next tile's b01, hides under C4 drain
        SP1();
        mm16<4, 2>(acc, a, b);    // a47 x b23 (b23 untouched by the pre-read)
        SP0();
        BAR(); FENCE();

        pAg += 64; pBg += 64;
    }

    // ---- epilogue: C/D layout col=lane&15, row=(lane>>4)*4+reg ----
#pragma unroll
    for (int f = 0; f < 8; ++f) {
        const int r0 = row0 + wm * 128 + f * 16 + q * 4;
#pragma unroll
        for (int n = 0; n < 4; ++n) {
            const int c = col0 + wn * 64 + n * 16 + ml;
            float* Cp = C + (size_t)r0 * NDIM + c;
#pragma unroll
            for (int r = 0; r < 4; ++r) Cp[(size_t)r * NDIM] = acc[f][n][r];
        }
    }
}

// ---------------- Fallback (only if ws too small): naive fp32 ----------------
__global__ __launch_bounds__(256) void gemm_fallback(const float* __restrict__ X,
                                                     const int* __restrict__ W,
                                                     const float* __restrict__ S,
                                                     float* __restrict__ C) {
    int n = blockIdx.x * 256 + threadIdx.x;
    int m = blockIdx.y;
    if (n >= NDIM) return;
    const float* xr = X + (size_t)m * KDIM;
    const int*   wr = W + (size_t)n * KDIM;
    float acc = 0.f;
    for (int g = 0; g < GDIM; ++g) {
        float s = S[n * GDIM + g];
        float part = 0.f;
        for (int k = 0; k < 128; ++k)
            part += xr[g * 128 + k] * (float)wr[g * 128 + k];
        acc += part * s;
    }
    C[(size_t)m * NDIM + n] = acc;
}

extern "C" void kernel_launch(void* const* d_in, const int* in_sizes, int n_in,
                              void* d_out, int out_size, void* d_ws, size_t ws_size,
                              hipStream_t stream) {
    const float* x  = (const float*)d_in[0];
    const int*   w  = (const int*)d_in[1];
    const float* sc = (const float*)d_in[2];
    float* out = (float*)d_out;

    const size_t bytesA = (size_t)MDIM * KDIM * 2;   // 64 MiB bf16 x
    const size_t bytesB = (size_t)NDIM * KDIM * 2;   // 86 MiB bf16 dequant w

    if (ws_size >= bytesA + bytesB) {
        unsigned short* Abf = (unsigned short*)d_ws;
        unsigned short* Bbf = (unsigned short*)((char*)d_ws + bytesA);

        prep_kernel<<<(unsigned)(XBLOCKS + WBLOCKS), 256, 0, stream>>>(x, w, sc, Abf, Bbf);
        gemm256<<<NWG, 512, 0, stream>>>(Abf, Bbf, out);
    } else {
        dim3 grid((NDIM + 255) / 256, MDIM);
        gemm_fallback<<<grid, 256, 0, stream>>>(x, w, sc, out);
    }
}

// Round 4
// 1171.399 us; speedup vs baseline: 1.0826x; 1.0015x over previous
//
#include <hip/hip_runtime.h>
#include <hip/hip_bf16.h>

// Problem constants (fixed by setup_inputs)
#define MDIM 8192    // B*S = 4*2048
#define KDIM 4096
#define NDIM 11008   // O
#define GDIM 32      // K/128 groups

// ---- 256x256x64 GEMM geometry ----
#define BM 256
#define BN 256
#define BK 64
#define NKT (KDIM / BK)      // 64 K-tiles
#define MT (MDIM / BM)       // 32
#define NT (NDIM / BN)       // 43
#define NWG (MT * NT)        // 1376 blocks (divisible by 8 -> XCD swizzle bijective)
#define CPX (NWG / 8)        // 172 blocks per XCD

typedef __attribute__((ext_vector_type(8))) short short8;
typedef __attribute__((ext_vector_type(4))) float f32x4;
typedef __attribute__((address_space(3))) unsigned char lds_u8;

__device__ __forceinline__ unsigned short f2bf(float f) {
    unsigned int u = __float_as_uint(f);
    u += 0x7FFFu + ((u >> 16) & 1u);   // round-to-nearest-even (inputs finite)
    return (unsigned short)(u >> 16);
}

__device__ __forceinline__ void async_ld16(const void* g, lds_u8* l) {
    __builtin_amdgcn_global_load_lds(
        (const __attribute__((address_space(1))) void*)g,
        (__attribute__((address_space(3))) void*)l, 16, 0, 0);
}

// stage one half-tile (128 rows x 64 cols bf16 = 16 KiB): 2 x global_load_lds / thread
__device__ __forceinline__ void stage_half(const unsigned short* src, lds_u8* dst) {
    async_ld16(src, dst);                             // rows  0..63  of the half
    async_ld16(src + (size_t)64 * KDIM, dst + 8192);  // rows 64..127
}

#define BAR()   __builtin_amdgcn_s_barrier()
#define FENCE() asm volatile("" ::: "memory")
#define VMW(n)  asm volatile("s_waitcnt vmcnt(" #n ")" ::: "memory")
#define SP1()   __builtin_amdgcn_s_setprio(1)
#define SP0()   __builtin_amdgcn_s_setprio(0)

// load A fragments FB..FB+3 (both K=32 slices) from swizzled LDS (into reusable a[])
template<int FB>
__device__ __forceinline__ void ldA4(short8 (&a)[4][2],
                                     const unsigned short* p0,
                                     const unsigned short* p1) {
#pragma unroll
    for (int f = 0; f < 4; ++f) {
        a[f][0] = *(const short8*)(p0 + (FB + f) * 1024);
        a[f][1] = *(const short8*)(p1 + (FB + f) * 1024);
    }
}

// load B fragment pair NB..NB+1 (both K=32 slices) into a 2-frag array
template<int NB>
__device__ __forceinline__ void ldB2(short8 (&bb)[2][2],
                                     const unsigned short* p0,
                                     const unsigned short* p1) {
#pragma unroll
    for (int n = 0; n < 2; ++n) {
        bb[n][0] = *(const short8*)(p0 + (NB + n) * 1024);
        bb[n][1] = *(const short8*)(p1 + (NB + n) * 1024);
    }
}

// one C-quadrant x K=64: 16 MFMA (ks outer -> consecutive MFMAs independent)
template<int FB, int NB>
__device__ __forceinline__ void mm16(f32x4 (&acc)[8][4],
                                     const short8 (&a)[4][2],
                                     const short8 (&bb)[2][2]) {
#pragma unroll
    for (int ks = 0; ks < 2; ++ks)
#pragma unroll
        for (int f = 0; f < 4; ++f)
#pragma unroll
            for (int n = 0; n < 2; ++n)
                acc[FB + f][NB + n] = __builtin_amdgcn_mfma_f32_16x16x32_bf16(
                    a[f][ks], bb[n][ks], acc[FB + f][NB + n], 0, 0, 0);
}

// ---------------- Fused prepass: x fp32->bf16  AND  w int8*scale->bf16 ----------------
#define XBLOCKS ((MDIM * (size_t)KDIM) / 8 / 256)           // 16384
#define WBLOCKS ((NDIM * (size_t)KDIM) / 8 / 256)           // 22016
__global__ __launch_bounds__(256) void prep_kernel(const float* __restrict__ x,
                                                   const int* __restrict__ w,
                                                   const float* __restrict__ sc,
                                                   unsigned short* __restrict__ xb,
                                                   unsigned short* __restrict__ wb) {
    size_t b = blockIdx.x;
    if (b < XBLOCKS) {
        size_t i = (b * 256 + threadIdx.x) * 8;
        float4 f0 = *(const float4*)(x + i);
        float4 f1 = *(const float4*)(x + i + 4);
        union { unsigned short u[8]; uint4 v; } p;
        p.u[0] = f2bf(f0.x); p.u[1] = f2bf(f0.y); p.u[2] = f2bf(f0.z); p.u[3] = f2bf(f0.w);
        p.u[4] = f2bf(f1.x); p.u[5] = f2bf(f1.y); p.u[6] = f2bf(f1.z); p.u[7] = f2bf(f1.w);
        *(uint4*)(xb + i) = p.v;
    } else {
        size_t base = ((b - XBLOCKS) * 256 + threadIdx.x) * 8;  // 8 consecutive k, one group
        int o = (int)(base >> 12);             // /4096
        int k = (int)(base & 4095);
        float s = sc[o * GDIM + (k >> 7)];
        int4 w0 = *(const int4*)(w + base);
        int4 w1 = *(const int4*)(w + base + 4);
        union { unsigned short u[8]; uint4 v; } p;
        p.u[0] = f2bf((float)w0.x * s); p.u[1] = f2bf((float)w0.y * s);
        p.u[2] = f2bf((float)w0.z * s); p.u[3] = f2bf((float)w0.w * s);
        p.u[4] = f2bf((float)w1.x * s); p.u[5] = f2bf((float)w1.y * s);
        p.u[6] = f2bf((float)w1.z * s); p.u[7] = f2bf((float)w1.w * s);
        *(uint4*)(wb + base) = p.v;
    }
}

// ---------------- GEMM: C[M][N] = A[M][K] * B[N][K]^T, 256^2 tile, 2-barrier/K-tile ----
// 512 threads = 8 waves (2M x 4N); per-wave output 128x64 = acc[8][4] f32x4.
// LDS 128 KiB: A[2 buf][16384e] at elem 0, B[2 buf][16384e] at elem 32768.
// 16x16x32 MFMA + 3-bit 16B-chunk XOR swizzle (measured conflict-free).
// ONLY 2 barriers per K-tile (vs 8): (1) join after C2 so B(kt+2) staging can't
// overwrite B(kt) while any wave still reads it (b reads are compiler-drained
// before their MFMA uses, which precede the barrier); (2) publish join after
// VMW(4) for tile kt+1's data. Waves drift between barriers -> ds_read port
// time overlaps MFMA windows across waves (m114) instead of serializing.
__global__ __launch_bounds__(512, 2) void gemm256(const unsigned short* __restrict__ A,
                                                  const unsigned short* __restrict__ B,
                                                  float* __restrict__ C) {
    __shared__ unsigned short lds[65536];   // 128 KiB

    const int tid  = threadIdx.x;
    const int wave = tid >> 6;
    const int lane = tid & 63;
    const int wm = wave >> 2, wn = wave & 3;
    const int q  = lane >> 4;          // k-quad within K=32 slice
    const int ml = lane & 15;          // m (A) / n (B) index within 16-tile
    const int s  = ml & 7;             // read-side swizzle term (= row&7)

    // ---- block swizzle: XCD-contiguous chunks, M-fastest within XCD ----
    const int p    = blockIdx.x;
    const int tix  = (p & 7) * CPX + (p >> 3);
    const int bm   = tix & 31;
    const int bn   = tix >> 5;
    const int row0 = bm * BM, col0 = bn * BN;

    // ---- ds_read bases (ushort elements) ----
    const int e0  = ((q    ) ^ s) * 8;             // ks=0 chunk, swizzled
    const int e1  = ((4 + q) ^ s) * 8;             // ks=1 chunk, swizzled
    const int rdA = wm * 8192 + ml * 64;
    const int rdB = 32768 + wn * 4096 + ml * 64;

    // ---- staging mapping: thread t -> row t>>3, phys 16B-slot t&7 ----
    const int rA = tid >> 3;                        // 0..63
    const int cS = (tid & 7) ^ (rA & 7);            // logical slot held at phys slot
    const unsigned short* gA = A + (size_t)(row0 + rA) * KDIM + cS * 8;
    const unsigned short* gB = B + (size_t)(col0 + rA) * KDIM + cS * 8;
    lds_u8* L8A = (lds_u8*)lds + tid * 16;          // A region byte base + my chunk
    lds_u8* L8B = L8A + 65536;                      // B region

    // ---- prologue: tile0 (A,B -> buf0) + tile1 (B -> buf1) ----
    stage_half(gA,                      L8A);
    stage_half(gA + (size_t)128 * KDIM, L8A + 16384);
    stage_half(gB,                      L8B);
    stage_half(gB + (size_t)128 * KDIM, L8B + 16384);
    stage_half(gB + 64,                      L8B + 32768);
    stage_half(gB + (size_t)128 * KDIM + 64, L8B + 32768 + 16384);
    const unsigned short* pAg = gA + 64;     // A source for tile kt+1
    const unsigned short* pBg = gB + 128;    // B source for tile kt+2
    VMW(4);                                  // tile0 complete; tile1 B in flight
    BAR(); FENCE();

    short8 a[4][2], b1[2][2], b2[2][2];
    f32x4 acc[8][4];
    const f32x4 z = {0.f, 0.f, 0.f, 0.f};
#pragma unroll
    for (int f = 0; f < 8; ++f)
#pragma unroll
        for (int n = 0; n < 4; ++n) acc[f][n] = z;

    // pre-read tile0's b01 (buf0)
    ldB2<0>(b1, lds + rdB + e0, lds + rdB + e1);

    for (int kt = 0; kt < NKT; ++kt) {
        const int cur = kt & 1;
        const unsigned short* Lc  = lds + cur * 16384;
        const unsigned short* pA0 = Lc + rdA + e0;
        const unsigned short* pA1 = Lc + rdA + e1;
        const unsigned short* pB0 = Lc + rdB + e0;
        const unsigned short* pB1 = Lc + rdB + e1;
        const unsigned short* Ln  = lds + (cur ^ 1) * 16384;   // next tile's buffer
        const unsigned short* pB0n = Ln + rdB + e0;
        const unsigned short* pB1n = Ln + rdB + e1;
        lds_u8* dA = L8A + (((kt + 1) & 1) << 15);   // A dest buffer (kt+1)
        lds_u8* dB = L8B + ((cur) << 15);            // B dest buffer (kt+2 == kt mod 2)
        const bool stA = (kt + 1 < NKT);
        const bool stB = (kt + 2 < NKT);

        // ---- top: a03 reads (8) | stage A(kt+1) both halves (4 vm) ----
        ldA4<0>(a, pA0, pA1);
        if (stA) {
            stage_half(pAg, dA);
            stage_half(pAg + (size_t)128 * KDIM, dA + 16384);
        }
        // C1: a03 x b01 (b01 pre-read at end of previous tile)
        SP1(); mm16<0, 0>(acc, a, b1); SP0();

        // b23 reads (4) then C2: a03 x b23
        ldB2<2>(b2, pB0, pB1);
        SP1(); mm16<0, 2>(acc, a, b2); SP0();

        // a47 reads (8, reuse a[]) issued BEFORE the join barrier -> drain under it
        ldA4<4>(a, pA0, pA1);

        BAR(); FENCE();    // join #1: all waves consumed b01/b23 -> B(kt) region free

        if (stB) {
            stage_half(pBg, dB);                               // B(kt+2) half0
            stage_half(pBg + (size_t)128 * KDIM, dB + 16384);  // B(kt+2) half1
        }

        // C3: a47 x b01 (a47 drained by compiler gate; issued pre-barrier)
        SP1(); mm16<4, 0>(acc, a, b1); SP0();

        if (stB)      { VMW(4); }   // drain B(kt+1)+A(kt+1) (8 oldest of 12); B(kt+2) in flight
        else if (stA) { VMW(0); }   // kt == NKT-2: only 8 outstanding, drain all
        BAR(); FENCE();             // join #2: tile kt+1 fully published

        if (stA) ldB2<0>(b1, pB0n, pB1n);   // pre-read b01(kt+1); hides under C4

        // C4: a47 x b23
        SP1(); mm16<4, 2>(acc, a, b2); SP0();

        pAg += 64; pBg += 64;
    }

    // ---- epilogue: C/D layout col=lane&15, row=(lane>>4)*4+reg ----
#pragma unroll
    for (int f = 0; f < 8; ++f) {
        const int r0 = row0 + wm * 128 + f * 16 + q * 4;
#pragma unroll
        for (int n = 0; n < 4; ++n) {
            const int c = col0 + wn * 64 + n * 16 + ml;
            float* Cp = C + (size_t)r0 * NDIM + c;
#pragma unroll
            for (int r = 0; r < 4; ++r) Cp[(size_t)r * NDIM] = acc[f][n][r];
        }
    }
}

// ---------------- Fallback (only if ws too small): naive fp32 ----------------
__global__ __launch_bounds__(256) void gemm_fallback(const float* __restrict__ X,
                                                     const int* __restrict__ W,
                                                     const float* __restrict__ S,
                                                     float* __restrict__ C) {
    int n = blockIdx.x * 256 + threadIdx.x;
    int m = blockIdx.y;
    if (n >= NDIM) return;
    const float* xr = X + (size_t)m * KDIM;
    const int*   wr = W + (size_t)n * KDIM;
    float acc = 0.f;
    for (int g = 0; g < GDIM; ++g) {
        float s = S[n * GDIM + g];
        float part = 0.f;
        for (int k = 0; k < 128; ++k)
            part += xr[g * 128 + k] * (float)wr[g * 128 + k];
        acc += part * s;
    }
    C[(size_t)m * NDIM + n] = acc;
}

extern "C" void kernel_launch(void* const* d_in, const int* in_sizes, int n_in,
                              void* d_out, int out_size, void* d_ws, size_t ws_size,
                              hipStream_t stream) {
    const float* x  = (const float*)d_in[0];
    const int*   w  = (const int*)d_in[1];
    const float* sc = (const float*)d_in[2];
    float* out = (float*)d_out;

    const size_t bytesA = (size_t)MDIM * KDIM * 2;   // 64 MiB bf16 x
    const size_t bytesB = (size_t)NDIM * KDIM * 2;   // 86 MiB bf16 dequant w

    if (ws_size >= bytesA + bytesB) {
        unsigned short* Abf = (unsigned short*)d_ws;
        unsigned short* Bbf = (unsigned short*)((char*)d_ws + bytesA);

        prep_kernel<<<(unsigned)(XBLOCKS + WBLOCKS), 256, 0, stream>>>(x, w, sc, Abf, Bbf);
        gemm256<<<NWG, 512, 0, stream>>>(Abf, Bbf, out);
    } else {
        dim3 grid((NDIM + 255) / 256, MDIM);
        gemm_fallback<<<grid, 256, 0, stream>>>(x, w, sc, out);
    }
}